// Round 1
// 1117.410 us; speedup vs baseline: 1.0543x; 1.0543x over previous
//
#include <hip/hip_runtime.h>

// LSTM: B=2048, T=4096, I=5, H=10, fp32. One wave per batch chain.
// QUAD LAYOUT: lane = 4*j + k  (j = hidden unit 0..9, k = gate 0..3 = i,f,g,o).
//  - gate gather (i/f/g/o to every lane of the quad) is DPP quad_perm broadcast
//    (VALU, ~8cy) instead of ds_bpermute (LDS pipe ~50cy + lgkmcnt(0) that also
//    drained the prefetched x ds_reads and serialized the step pipeline).
//  - W_ih/W_hh/bias pre-scaled by -log2e (-2log2e for g rows): gate exp2 takes
//    the accumulator directly (no acc*k mul on the chain).
//  - cell state carried as cs = -2*log2e*c: output-tanh exp2 takes cs directly
//    (no cval*k mul on the chain). g-gate activation emits KC*tanh to keep the
//    carry consistent: cs' = f*cs + i*(KC*g).
// x staged global->LDS in 256-step double-buffered chunks (float4 loads issued
// a full chunk ahead); per-step x reads are uniform ds_read broadcasts.
// h-broadcast uses v_readlane from lanes 4*j (constant idx, VALU not DS).

#define BB 2048
#define TT 4096
#define II 5
#define HH 10
#define CH 256                // timesteps per LDS chunk
#define CHF (CH * II)         // 1280 floats = 5120 B per buffer
#define NCHUNK (TT / CH)      // 16

__device__ __forceinline__ float readlane_f(float v, int l) {
    union { float f; int i; } u;
    u.f = v;
    u.i = __builtin_amdgcn_readlane(u.i, l);
    return u.f;
}

// Broadcast quad element E to all 4 lanes of each quad (DPP quad_perm).
template<int E>
__device__ __forceinline__ float quad_bcast(float v) {
    union { float f; int i; } u;
    u.f = v;
    u.i = __builtin_amdgcn_update_dpp(u.i, u.i, E * 0x55, 0xF, 0xF, false);
    return u.f;
}

__global__ __launch_bounds__(64) void lstm_wave_kernel(
    const float* __restrict__ x,
    const float* __restrict__ h0,
    const float* __restrict__ c0,
    const float* __restrict__ W_ih,
    const float* __restrict__ W_hh,
    const float* __restrict__ b_ih,
    const float* __restrict__ b_hh,
    float* __restrict__ out)
{
    __shared__ float xs[2][CHF];   // 10 KiB / block; 8 blocks/CU -> 80 KiB

    const int b = blockIdx.x;
    const int lane = threadIdx.x;
    const int j = lane >> 2;       // hidden unit
    const int k = lane & 3;        // gate: 0=i 1=f 2=g 3=o
    const bool active = (lane < 4 * HH);

    const float LOG2E = 1.4426950408889634f;
    const float KC = -2.f * LOG2E;                 // cell carry scale
    const float scale = (k == 2) ? KC : -LOG2E;    // preact scale folded into W

    // Per-lane gate-row weights, pre-scaled
    float wih[II];
    float whh[HH];
    float bias = 0.f;
    if (active) {
        const int row = k * HH + j;                // gate blocks of 10 rows: i,f,g,o
#pragma unroll
        for (int q = 0; q < II; q++) wih[q] = W_ih[row * II + q] * scale;
#pragma unroll
        for (int q = 0; q < HH; q++) whh[q] = W_hh[row * HH + q] * scale;
        bias = (b_ih[row] + b_hh[row]) * scale;
    } else {
#pragma unroll
        for (int q = 0; q < II; q++) wih[q] = 0.f;
#pragma unroll
        for (int q = 0; q < HH; q++) whh[q] = 0.f;
    }

    // act = fma(s, am, ac) with s = rcp(1+exp2(acc)):
    //   sigmoid lanes: act = s.   g lane: act = KC*tanh = s*(2KC) + (-KC)
    const float am = (k == 2) ? (2.f * KC) : 1.f;
    const float ac = (k == 2) ? (-KC) : 0.f;

    float hval = 0.f, cs = 0.f;
    if (active) {
        hval = h0[b * HH + j];
        cs   = c0[b * HH + j] * KC;    // carry is KC*c
    }

    const float* xrow = x + (size_t)b * TT * II;
    float* orow = out + (size_t)b * TT * HH;
    const bool do_store = active && (k == 0);   // lanes 0,4,...,36 store h[j]

    // ---- stage chunk 0 ----
    float4 pf0, pf1, pf2, pf3, pf4;
    {
        const float4* xv = (const float4*)xrow;
        pf0 = xv[0 * 64 + lane];
        pf1 = xv[1 * 64 + lane];
        pf2 = xv[2 * 64 + lane];
        pf3 = xv[3 * 64 + lane];
        pf4 = xv[4 * 64 + lane];
        float4* dst = (float4*)xs[0];
        dst[0 * 64 + lane] = pf0;
        dst[1 * 64 + lane] = pf1;
        dst[2 * 64 + lane] = pf2;
        dst[3 * 64 + lane] = pf3;
        dst[4 * 64 + lane] = pf4;
    }

    for (int c = 0; c < NCHUNK; ++c) {
        const float* xc = xs[c & 1];

        // issue next chunk's global loads now; consume ~256 steps later
        if (c + 1 < NCHUNK) {
            const float4* xv = (const float4*)(xrow + (size_t)(c + 1) * CHF);
            pf0 = xv[0 * 64 + lane];
            pf1 = xv[1 * 64 + lane];
            pf2 = xv[2 * 64 + lane];
            pf3 = xv[3 * 64 + lane];
            pf4 = xv[4 * 64 + lane];
        }

#pragma unroll 8
        for (int u = 0; u < CH; ++u) {
            const int t = c * CH + u;

            // x_t from LDS (uniform address -> broadcast, no conflicts)
            const float x0 = xc[u * II + 0];
            const float x1 = xc[u * II + 1];
            const float x2 = xc[u * II + 2];
            const float x3 = xc[u * II + 3];
            const float x4 = xc[u * II + 4];

            // pre-scaled gate preact: 4-acc tree; x terms land first (off-chain)
            float a0 = fmaf(x0, wih[0], bias);
            float a1 = x1 * wih[1];
            float a2 = x2 * wih[2];
            float a3 = x3 * wih[3];
            a0 = fmaf(x4, wih[4], a0);

            a0 = fmaf(readlane_f(hval, 0),  whh[0], a0);
            a1 = fmaf(readlane_f(hval, 4),  whh[1], a1);
            a2 = fmaf(readlane_f(hval, 8),  whh[2], a2);
            a3 = fmaf(readlane_f(hval, 12), whh[3], a3);
            a0 = fmaf(readlane_f(hval, 16), whh[4], a0);
            a1 = fmaf(readlane_f(hval, 20), whh[5], a1);
            a2 = fmaf(readlane_f(hval, 24), whh[6], a2);
            a3 = fmaf(readlane_f(hval, 28), whh[7], a3);
            a0 = fmaf(readlane_f(hval, 32), whh[8], a0);
            a1 = fmaf(readlane_f(hval, 36), whh[9], a1);
            const float acc = (a0 + a1) + (a2 + a3);

            // branchless sigmoid / KC*tanh; exp2 input needs no scaling mul
            const float e = __builtin_amdgcn_exp2f(acc);
            const float s = __builtin_amdgcn_rcpf(1.f + e);
            const float act = fmaf(s, am, ac);

            // quad gather: pure-VALU DPP broadcasts, no LDS pipe
            const float iv = quad_bcast<0>(act);
            const float fv = quad_bcast<1>(act);
            const float gs = quad_bcast<2>(act);   // already KC*g
            const float ov = quad_bcast<3>(act);

            // cs = KC*c:  cs' = f*cs + i*(KC*g);  tanh(c) = 2*rcp(1+exp2(cs))-1
            cs = fmaf(fv, cs, iv * gs);
            const float e2 = __builtin_amdgcn_exp2f(cs);
            const float th = fmaf(__builtin_amdgcn_rcpf(1.f + e2), 2.f, -1.f);
            hval = ov * th;

            if (do_store) orow[t * HH + j] = hval;
        }

        // park the prefetched chunk into the other LDS buffer
        if (c + 1 < NCHUNK) {
            float4* dst = (float4*)xs[(c + 1) & 1];
            dst[0 * 64 + lane] = pf0;
            dst[1 * 64 + lane] = pf1;
            dst[2 * 64 + lane] = pf2;
            dst[3 * 64 + lane] = pf3;
            dst[4 * 64 + lane] = pf4;
        }
    }
}

extern "C" void kernel_launch(void* const* d_in, const int* in_sizes, int n_in,
                              void* d_out, int out_size, void* d_ws, size_t ws_size,
                              hipStream_t stream) {
    const float* x    = (const float*)d_in[0];
    const float* h0   = (const float*)d_in[1];
    const float* c0   = (const float*)d_in[2];
    const float* W_ih = (const float*)d_in[3];
    const float* W_hh = (const float*)d_in[4];
    const float* b_ih = (const float*)d_in[5];
    const float* b_hh = (const float*)d_in[6];
    float* out = (float*)d_out;

    lstm_wave_kernel<<<dim3(BB), dim3(64), 0, stream>>>(
        x, h0, c0, W_ih, W_hh, b_ih, b_hh, out);
}

// Round 7
// 1058.607 us; speedup vs baseline: 1.1129x; 1.0555x over previous
//
#include <hip/hip_runtime.h>

// LSTM: B=2048, T=4096, I=5, H=10, fp32. One wave per batch chain.
// QUAD LAYOUT: lane = 4*j + k  (j = hidden unit 0..9, k = gate 0..3 = i,f,g,o).
//  - gate gather is DPP quad_perm broadcast (VALU), no LDS pipe on the chain.
//  - W_ih/W_hh/bias pre-scaled by -log2e (-2log2e for g rows); cell carried as
//    cs = -2*log2e*c, so both exp2's consume their inputs directly.
// Diet (this round):
//  - x staged into PADDED LDS (8 floats/step): per-step reads are 1 ds_read_b128
//    + 1 ds_read_b32 (uniform -> broadcast) instead of 5 ds_read_b32. The 20
//    scatter addresses for staging are precomputed once (magic-div hoisted).
//  - stores batched 4 steps: lane (j,k) captures hval at steps ==k (mod 4) via
//    one cndmask (mask hoisted), all 40 lanes store every 4th step -> one
//    coalesced 160B segment, running pointer += 320B per unroll-8. Kills the
//    per-step t*HH + 64-bit address math and per-step exec juggling.

#define BB 2048
#define TT 4096
#define II 5
#define HH 10
#define CH 256                // timesteps per LDS chunk
#define CHF (CH * II)         // 1280 floats of raw x per chunk
#define PSTRIDE 32            // padded bytes per step in LDS (8 floats)
#define BUFB (CH * PSTRIDE)   // 8192 bytes per buffer
#define NCHUNK (TT / CH)      // 16

__device__ __forceinline__ float readlane_f(float v, int l) {
    union { float f; int i; } u;
    u.f = v;
    u.i = __builtin_amdgcn_readlane(u.i, l);
    return u.f;
}

// Broadcast quad element E to all 4 lanes of each quad (DPP quad_perm).
template<int E>
__device__ __forceinline__ float quad_bcast(float v) {
    union { float f; int i; } u;
    u.f = v;
    u.i = __builtin_amdgcn_update_dpp(u.i, u.i, E * 0x55, 0xF, 0xF, false);
    return u.f;
}

__global__ __launch_bounds__(64) void lstm_wave_kernel(
    const float* __restrict__ x,
    const float* __restrict__ h0,
    const float* __restrict__ c0,
    const float* __restrict__ W_ih,
    const float* __restrict__ W_hh,
    const float* __restrict__ b_ih,
    const float* __restrict__ b_hh,
    float* __restrict__ out)
{
    __shared__ __align__(16) char xs[2][BUFB];   // 16 KiB/block; 8 blocks/CU

    const int b = blockIdx.x;
    const int lane = threadIdx.x;
    const int j = lane >> 2;       // hidden unit
    const int k = lane & 3;        // gate: 0=i 1=f 2=g 3=o
    const bool active = (lane < 4 * HH);

    const float LOG2E = 1.4426950408889634f;
    const float KC = -2.f * LOG2E;                 // cell carry scale
    const float scale = (k == 2) ? KC : -LOG2E;    // preact scale folded into W

    // Per-lane gate-row weights, pre-scaled
    float wih[II];
    float whh[HH];
    float bias = 0.f;
    if (active) {
        const int row = k * HH + j;                // gate blocks of 10 rows: i,f,g,o
#pragma unroll
        for (int q = 0; q < II; q++) wih[q] = W_ih[row * II + q] * scale;
#pragma unroll
        for (int q = 0; q < HH; q++) whh[q] = W_hh[row * HH + q] * scale;
        bias = (b_ih[row] + b_hh[row]) * scale;
    } else {
#pragma unroll
        for (int q = 0; q < II; q++) wih[q] = 0.f;
#pragma unroll
        for (int q = 0; q < HH; q++) whh[q] = 0.f;
    }

    // act = fma(s, am, ac) with s = rcp(1+exp2(acc)):
    //   sigmoid lanes: act = s.   g lane: act = KC*tanh = s*(2KC) + (-KC)
    const float am = (k == 2) ? (2.f * KC) : 1.f;
    const float ac = (k == 2) ? (-KC) : 0.f;

    float hval = 0.f, cs = 0.f;
    if (active) {
        hval = h0[b * HH + j];
        cs   = c0[b * HH + j] * KC;    // carry is KC*c
    }

    const float* xrow = x + (size_t)b * TT * II;

    // Per-lane batched-store pointer: lane (j,k) writes out[b][tb+k][j].
    float* outp = out + (size_t)b * TT * HH + k * HH + j;

    // Precompute the 20 padded-LDS scatter byte-addresses for staging:
    // loaded float4 xv[q*64+lane] component c sits at raw float pos
    // p = (q*64+lane)*4 + c  ->  padded byte (p/5)*32 + (p%5)*4.
    int wa[II][4];
#pragma unroll
    for (int q = 0; q < II; q++) {
#pragma unroll
        for (int c4 = 0; c4 < 4; c4++) {
            const int p = (q * 64 + lane) * 4 + c4;
            wa[q][c4] = (p / II) * PSTRIDE + (p % II) * 4;
        }
    }

    // ---- stage chunk 0 (padded scatter) ----
    float4 pf[II];
    {
        const float4* xv = (const float4*)xrow;
#pragma unroll
        for (int q = 0; q < II; q++) pf[q] = xv[q * 64 + lane];
        char* dst = xs[0];
#pragma unroll
        for (int q = 0; q < II; q++) {
            *(float*)(dst + wa[q][0]) = pf[q].x;
            *(float*)(dst + wa[q][1]) = pf[q].y;
            *(float*)(dst + wa[q][2]) = pf[q].z;
            *(float*)(dst + wa[q][3]) = pf[q].w;
        }
    }

    float keep = 0.f;   // batched-store capture register

    for (int c = 0; c < NCHUNK; ++c) {
        const char* xc = xs[c & 1];

        // issue next chunk's global loads now; consume ~256 steps later
        if (c + 1 < NCHUNK) {
            const float4* xv = (const float4*)(xrow + (size_t)(c + 1) * CHF);
#pragma unroll
            for (int q = 0; q < II; q++) pf[q] = xv[q * 64 + lane];
        }

#pragma unroll 8
        for (int u = 0; u < CH; ++u) {
            // x_t from padded LDS (uniform address -> broadcast)
            const float4 xv4 = *(const float4*)(xc + u * PSTRIDE);
            const float x4v  = *(const float*)(xc + u * PSTRIDE + 16);

            // pre-scaled gate preact: 4-acc tree; x terms land first (off-chain)
            float a0 = fmaf(xv4.x, wih[0], bias);
            float a1 = xv4.y * wih[1];
            float a2 = xv4.z * wih[2];
            float a3 = xv4.w * wih[3];
            a0 = fmaf(x4v, wih[4], a0);

            a0 = fmaf(readlane_f(hval, 0),  whh[0], a0);
            a1 = fmaf(readlane_f(hval, 4),  whh[1], a1);
            a2 = fmaf(readlane_f(hval, 8),  whh[2], a2);
            a3 = fmaf(readlane_f(hval, 12), whh[3], a3);
            a0 = fmaf(readlane_f(hval, 16), whh[4], a0);
            a1 = fmaf(readlane_f(hval, 20), whh[5], a1);
            a2 = fmaf(readlane_f(hval, 24), whh[6], a2);
            a3 = fmaf(readlane_f(hval, 28), whh[7], a3);
            a0 = fmaf(readlane_f(hval, 32), whh[8], a0);
            a1 = fmaf(readlane_f(hval, 36), whh[9], a1);
            const float acc = (a0 + a1) + (a2 + a3);

            // branchless sigmoid / KC*tanh
            const float e = __builtin_amdgcn_exp2f(acc);
            const float s = __builtin_amdgcn_rcpf(1.f + e);
            const float act = fmaf(s, am, ac);

            // quad gather: pure-VALU DPP broadcasts
            const float iv = quad_bcast<0>(act);
            const float fv = quad_bcast<1>(act);
            const float gs = quad_bcast<2>(act);   // already KC*g
            const float ov = quad_bcast<3>(act);

            // cs = KC*c:  cs' = f*cs + i*(KC*g);  tanh(c) = 2*rcp(1+exp2(cs))-1
            cs = fmaf(fv, cs, iv * gs);
            const float e2 = __builtin_amdgcn_exp2f(cs);
            const float th = fmaf(__builtin_amdgcn_rcpf(1.f + e2), 2.f, -1.f);
            hval = ov * th;

            // batched store: lane (j,k) captures step ==k (mod 4);
            // 40 lanes store a contiguous 160B segment every 4th step.
            keep = ((u & 3) == k) ? hval : keep;     // cndmask, masks hoisted
            if ((u & 3) == 3) {
                const int off = ((u & 7) == 3) ? 0 : 40;   // imm 0 / 160B
                if (active) outp[off] = keep;
            }
            if ((u & 7) == 7) outp += 80;            // +320B per unroll-8
        }

        // park the prefetched chunk into the other LDS buffer (padded scatter)
        if (c + 1 < NCHUNK) {
            char* dst = xs[(c + 1) & 1];
#pragma unroll
            for (int q = 0; q < II; q++) {
                *(float*)(dst + wa[q][0]) = pf[q].x;
                *(float*)(dst + wa[q][1]) = pf[q].y;
                *(float*)(dst + wa[q][2]) = pf[q].z;
                *(float*)(dst + wa[q][3]) = pf[q].w;
            }
        }
    }
}

extern "C" void kernel_launch(void* const* d_in, const int* in_sizes, int n_in,
                              void* d_out, int out_size, void* d_ws, size_t ws_size,
                              hipStream_t stream) {
    const float* x    = (const float*)d_in[0];
    const float* h0   = (const float*)d_in[1];
    const float* c0   = (const float*)d_in[2];
    const float* W_ih = (const float*)d_in[3];
    const float* W_hh = (const float*)d_in[4];
    const float* b_ih = (const float*)d_in[5];
    const float* b_hh = (const float*)d_in[6];
    float* out = (float*)d_out;

    lstm_wave_kernel<<<dim3(BB), dim3(64), 0, stream>>>(
        x, h0, c0, W_ih, W_hh, b_ih, b_hh, out);
}